// Round 4
// baseline (193.946 us; speedup 1.0000x reference)
//
#include <hip/hip_runtime.h>
#include <hip/hip_bf16.h>

#define NB 64      // batch
#define NT 64      // time
#define NA 64      // action dim
#define NH 1024    // hidden
#define NE 32      // embodiments
#define K2DIM 2048 // 2H

typedef unsigned short bf16_t;
typedef __attribute__((ext_vector_type(8))) short bf16x8;  // 8 bf16 = 4 VGPRs
typedef __attribute__((ext_vector_type(4))) short s16x4;   // 4 bf16 = 2 VGPRs
typedef __attribute__((ext_vector_type(4))) float f32x4;   // MFMA accumulator

__device__ __forceinline__ bf16_t f32_to_bf16(float f) {
    unsigned int u = __float_as_uint(f);
    u = (u + 0x7FFFu + ((u >> 16) & 1u)) >> 16;   // round-to-nearest-even
    return (bf16_t)u;
}
__device__ __forceinline__ unsigned cvt2(float x, float y) {
    unsigned short a = __builtin_bit_cast(unsigned short, __float2bfloat16(x));
    unsigned short b = __builtin_bit_cast(unsigned short, __float2bfloat16(y));
    return (unsigned)a | ((unsigned)b << 16);
}

// ---------------------------------------------------------------------------
// Scheduler: group batches by cat (groups of <=4). groups[g*8] = {cat, nb,
// b0..b3, pad, pad}; nb==0 -> inactive. Deterministic in cat_ids only.
// 1 block, 64 threads.
// ---------------------------------------------------------------------------
__global__ void make_groups(const int* __restrict__ cat_ids,
                            int* __restrict__ groups)
{
    __shared__ int keys[NB], order[NB], catv[NB];
    __shared__ int gcat[NB], gnb[NB], gb[NB][4];
    __shared__ int sng;

    const int tid = threadIdx.x;   // 0..63
    int c = cat_ids[tid];
    catv[tid] = c;
    keys[tid] = c * 64 + tid;      // unique key, stable within cat
    __syncthreads();

    int mykey = keys[tid];
    int rank = 0;
    for (int j = 0; j < NB; ++j) rank += (keys[j] < mykey) ? 1 : 0;
    order[rank] = tid;
    __syncthreads();

    if (tid == 0) {
        int ng = 0, prev = -1, cnt = 4;
        for (int i = 0; i < NB; ++i) {
            int b  = order[i];
            int cb = catv[b];
            if (cb != prev || cnt == 4) {
                gcat[ng] = cb; gnb[ng] = 0; cnt = 0; prev = cb; ++ng;
            }
            gb[ng - 1][cnt] = b;
            ++cnt; gnb[ng - 1] = cnt;
        }
        sng = ng;
    }
    __syncthreads();

    int ng = sng;
    int base = tid * 8;
    if (tid < ng) {
        int nbv = gnb[tid];
        groups[base + 0] = gcat[tid];
        groups[base + 1] = nbv;
        #pragma unroll
        for (int s = 0; s < 4; ++s)
            groups[base + 2 + s] = gb[tid][s < nbv ? s : 0];  // pad w/ b0
        groups[base + 6] = 0; groups[base + 7] = 0;
    } else {
        #pragma unroll
        for (int s = 0; s < 8; ++s) groups[base + s] = 0;     // nb = 0
    }
}

// ---------------------------------------------------------------------------
// K1: a_emb = actions @ W1[cat] + b1 (K=64) and sinusoidal PE, fused.
// Writes x = concat(a_emb, pe) as bf16 [B][T][2H]. grid (B, H/64), block 256.
// ---------------------------------------------------------------------------
__global__ __launch_bounds__(256) void k1_embed(
    const float* __restrict__ actions, const float* __restrict__ W1,
    const float* __restrict__ b1, const int* __restrict__ timesteps,
    const int* __restrict__ cat_ids, bf16_t* __restrict__ x)
{
    __shared__ float act[NT][NA];
    __shared__ float pe[64];

    const int b   = blockIdx.x;
    const int c0  = blockIdx.y * 64;
    const int tid = threadIdx.x;
    const int cat = cat_ids[b];
    const float ts = (float)timesteps[b];

    const float* ab = actions + b * (NT * NA);
    #pragma unroll
    for (int p = 0; p < 16; ++p) {
        int idx = tid + p * 256;
        act[idx >> 6][idx & 63] = ab[idx];
    }
    if (tid < 64) {
        const float kfreq = logf(10000.0f) / 512.0f;
        int c = c0 + tid;
        float v;
        if (c < 512) v = sinf(ts * expf(-(float)c * kfreq));
        else         v = cosf(ts * expf(-(float)(c - 512) * kfreq));
        pe[tid] = v;
    }
    __syncthreads();

    const int cc = tid & 63;
    const int c  = c0 + cc;
    const int t0 = tid >> 6;

    float acc[16];
    const float bias = b1[cat * NH + c];
    #pragma unroll
    for (int i = 0; i < 16; ++i) acc[i] = bias;

    const float* Wp = W1 + (size_t)cat * (NA * NH) + c;
    #pragma unroll 8
    for (int k = 0; k < NA; ++k) {
        float w = Wp[(size_t)k * NH];
        #pragma unroll
        for (int i = 0; i < 16; ++i)
            acc[i] = fmaf(act[t0 + 4 * i][k], w, acc[i]);
    }

    bf16_t* xb = x + (size_t)b * (NT * K2DIM);
    const bf16_t pv = f32_to_bf16(pe[cc]);
    #pragma unroll
    for (int i = 0; i < 16; ++i) {
        int t = t0 + 4 * i;
        xb[(size_t)t * K2DIM + c]      = f32_to_bf16(acc[i]);
        xb[(size_t)t * K2DIM + NH + c] = pv;
    }
}

// ---------------------------------------------------------------------------
// Grouped MFMA GEMM: for group g (<=4 same-cat batches), n-tile of 128:
// out[b_s, t, n] = xin[b_s, t, :] @ W[cat] + bias[cat]   (+ optional swish)
// Block: M = 4*64 rows (4 batch slots) x 128 n. 512 threads = 8 waves as
// 4m x 2n; wave tile 64x64 = 4x4 16x16x32 frags.
// LDS per 64-k chunk: xs 4 slots x [64t][64k] swizzled (32 KB) +
// wsm k-major subtiled [k/4][n/16][4][16] (16 KB), B via ds_read_b64_tr_b16.
// One-chunk-ahead register prefetch hides HBM-miss latency of the W stream.
// ---------------------------------------------------------------------------
template<int KDIM, bool SWISH, typename OutT>
__global__ __launch_bounds__(512) void gemm_grouped(
    const bf16_t* __restrict__ xin, const float* __restrict__ W,
    const float* __restrict__ bias, const int* __restrict__ groups,
    OutT* __restrict__ out)
{
    __shared__ __align__(128) char xs[4 * 8192];   // 32 KB
    __shared__ __align__(128) char wsm[16384];     // 16 KB

    const int* grp = groups + blockIdx.x * 8;
    const int nb = grp[1];
    if (nb == 0) return;
    const int cat = grp[0];
    int bslot[4];
    #pragma unroll
    for (int s = 0; s < 4; ++s) bslot[s] = grp[2 + s];

    const int n0   = blockIdx.y * 128;
    const int tid  = threadIdx.x;
    const int lane = tid & 63;
    const int wv   = tid >> 6;           // 0..7
    const int l15  = lane & 15;
    const int l4   = lane >> 4;
    const int msl  = wv & 3;             // batch slot of this wave
    const int pw   = (wv >> 2) * 4;      // n16-subtile offset of this wave
    const int ncol0 = n0 + (wv >> 2) * 64;

    constexpr int NK = KDIM / 64;

    // --- staging assignments (fixed per thread) ---
    // x: thread stages element (t = tid>>3, k8 = tid&7) for each of 4 slots
    const int xt  = tid >> 3;
    const int xk8 = tid & 7;
    const int xoff = ((xt * 128 + xk8 * 16) ^ ((xt & 7) << 4));
    const bf16_t* xsrc[4];
    #pragma unroll
    for (int p = 0; p < 4; ++p)
        xsrc[p] = xin + ((size_t)bslot[p] * NT + xt) * KDIM + xk8 * 8;
    // W: thread stages k-rows (tid>>4) and (tid>>4)+32, oct = tid&15
    const int wk  = tid >> 4;
    const int oct = tid & 15;
    const float* Wt0 = W + (size_t)cat * KDIM * NH + n0
                         + (size_t)wk * NH + oct * 8;
    int woff[2];
    #pragma unroll
    for (int p = 0; p < 2; ++p) {
        int kk = wk + 32 * p;
        woff[p] = ((kk >> 2) * 8 + (oct >> 1)) * 128 + (kk & 3) * 32 + (oct & 1) * 16;
    }

    f32x4 acc[4][4];
    #pragma unroll
    for (int nf = 0; nf < 4; ++nf) {
        float bv = bias[(size_t)cat * NH + ncol0 + nf * 16 + l15];
        #pragma unroll
        for (int mf = 0; mf < 4; ++mf)
            acc[mf][nf] = (f32x4){bv, bv, bv, bv};
    }

    const unsigned wbase = (unsigned)(unsigned long long)&wsm[0];
    const unsigned laneB = wbase + (unsigned)(l4 * 2048 + l15 * 8);
    const int aslot = msl * 8192;

    uint4  xr[4];
    float4 wr[4];

    auto LOAD = [&](int kc) {
        #pragma unroll
        for (int p = 0; p < 4; ++p)
            xr[p] = *(const uint4*)(xsrc[p] + (size_t)kc * 64);
        #pragma unroll
        for (int p = 0; p < 2; ++p) {
            const float* s = Wt0 + (size_t)(kc * 64 + 32 * p) * NH;
            wr[2 * p]     = *(const float4*)(s);
            wr[2 * p + 1] = *(const float4*)(s + 4);
        }
    };
    auto WRITE = [&]() {
        #pragma unroll
        for (int p = 0; p < 4; ++p)
            *(uint4*)(xs + xoff + p * 8192) = xr[p];
        #pragma unroll
        for (int p = 0; p < 2; ++p) {
            uint4 pk;
            pk.x = cvt2(wr[2 * p].x,     wr[2 * p].y);
            pk.y = cvt2(wr[2 * p].z,     wr[2 * p].w);
            pk.z = cvt2(wr[2 * p + 1].x, wr[2 * p + 1].y);
            pk.w = cvt2(wr[2 * p + 1].z, wr[2 * p + 1].w);
            *(uint4*)(wsm + woff[p]) = pk;
        }
    };

    LOAD(0);
    for (int kc = 0; kc < NK; ++kc) {
        __syncthreads();                 // consumers of prev chunk done
        WRITE();
        __syncthreads();                 // LDS ready
        if (kc + 1 < NK) LOAD(kc + 1);   // prefetch flies under the MFMAs

        #pragma unroll
        for (int ks = 0; ks < 2; ++ks) {
            bf16x8 af[4], bfr[4];
            #pragma unroll
            for (int mf = 0; mf < 4; ++mf) {
                int row = mf * 16 + l15;
                int off = aslot + ((row * 128 + ks * 64 + l4 * 16) ^ ((row & 7) << 4));
                af[mf] = *(const bf16x8*)(xs + off);
            }
            #pragma unroll
            for (int nf = 0; nf < 4; ++nf) {
                unsigned a = laneB + (unsigned)(ks * 8192 + (pw + nf) * 128);
                s16x4 lo, hi;
                asm volatile("ds_read_b64_tr_b16 %0, %1" : "=v"(lo) : "v"(a));
                asm volatile("ds_read_b64_tr_b16 %0, %1 offset:1024" : "=v"(hi) : "v"(a));
                bfr[nf] = __builtin_shufflevector(lo, hi, 0, 1, 2, 3, 4, 5, 6, 7);
            }
            asm volatile("s_waitcnt lgkmcnt(0)" ::: "memory");
            __builtin_amdgcn_sched_barrier(0);
            #pragma unroll
            for (int mf = 0; mf < 4; ++mf)
                #pragma unroll
                for (int nf = 0; nf < 4; ++nf)
                    acc[mf][nf] = __builtin_amdgcn_mfma_f32_16x16x32_bf16(
                        af[mf], bfr[nf], acc[mf][nf], 0, 0, 0);
        }
    }

    // epilogue: C/D layout col = lane&15, row = (lane>>4)*4 + reg
    const int bout = bslot[msl];
    #pragma unroll
    for (int mf = 0; mf < 4; ++mf) {
        #pragma unroll
        for (int nf = 0; nf < 4; ++nf) {
            int col = ncol0 + nf * 16 + l15;
            #pragma unroll
            for (int r = 0; r < 4; ++r) {
                int trow = mf * 16 + l4 * 4 + r;
                float h = acc[mf][nf][r];
                if (SWISH) h = h / (1.0f + __expf(-h));
                if constexpr (sizeof(OutT) == 2) {
                    out[((size_t)bout * NT + trow) * NH + col] = (OutT)f32_to_bf16(h);
                } else {
                    out[((size_t)bout * NT + trow) * NH + col] = h;
                }
            }
        }
    }
}

extern "C" void kernel_launch(void* const* d_in, const int* in_sizes, int n_in,
                              void* d_out, int out_size, void* d_ws, size_t ws_size,
                              hipStream_t stream) {
    const float* actions   = (const float*)d_in[0];
    const float* W1        = (const float*)d_in[1];
    const float* b1        = (const float*)d_in[2];
    const float* W2        = (const float*)d_in[3];
    const float* b2        = (const float*)d_in[4];
    const float* W3        = (const float*)d_in[5];
    const float* b3        = (const float*)d_in[6];
    const int*   timesteps = (const int*)d_in[7];
    const int*   cat_ids   = (const int*)d_in[8];
    float* out = (float*)d_out;

    // ws: x bf16 [B][T][2H] (16.8 MB), y bf16 [B][T][H] (8.4 MB), groups (2 KB)
    bf16_t* x = (bf16_t*)d_ws;
    bf16_t* y = x + (size_t)NB * NT * K2DIM;
    int* groups = (int*)(y + (size_t)NB * NT * NH);

    make_groups<<<1, 64, 0, stream>>>(cat_ids, groups);
    k1_embed<<<dim3(NB, NH / 64), 256, 0, stream>>>(actions, W1, b1, timesteps, cat_ids, x);
    gemm_grouped<K2DIM, true,  bf16_t><<<dim3(64, NH / 128), 512, 0, stream>>>(x, W2, b2, groups, y);
    gemm_grouped<NH,    false, float ><<<dim3(64, NH / 128), 512, 0, stream>>>(y, W3, b3, groups, out);
}

// Round 5
// 176.736 us; speedup vs baseline: 1.0974x; 1.0974x over previous
//
#include <hip/hip_runtime.h>
#include <hip/hip_bf16.h>

#define NB 64      // batch
#define NT 64      // time
#define NA 64      // action dim
#define NH 1024    // hidden
#define NE 32      // embodiments
#define K2DIM 2048 // 2H

typedef unsigned short bf16_t;
typedef __attribute__((ext_vector_type(8))) short bf16x8;  // 8 bf16 = 4 VGPRs
typedef __attribute__((ext_vector_type(4))) short s16x4;   // 4 bf16 = 2 VGPRs
typedef __attribute__((ext_vector_type(4))) float f32x4;   // MFMA accumulator

__device__ __forceinline__ bf16_t f32_to_bf16(float f) {
    unsigned int u = __float_as_uint(f);
    u = (u + 0x7FFFu + ((u >> 16) & 1u)) >> 16;   // round-to-nearest-even
    return (bf16_t)u;
}
__device__ __forceinline__ unsigned cvt2(float x, float y) {
    unsigned short a = __builtin_bit_cast(unsigned short, __float2bfloat16(x));
    unsigned short b = __builtin_bit_cast(unsigned short, __float2bfloat16(y));
    return (unsigned)a | ((unsigned)b << 16);
}

// ---------------------------------------------------------------------------
// Scheduler: group batches by cat into PAIRS (<=2). groups[g*8] = {cat, nb,
// b0, b1, 0,0,0,0}; nb==0 -> inactive. Deterministic in cat_ids only.
// ---------------------------------------------------------------------------
__global__ void make_groups(const int* __restrict__ cat_ids,
                            int* __restrict__ groups)
{
    __shared__ int keys[NB], order[NB], catv[NB];
    __shared__ int gcat[NB], gnb[NB], gb[NB][2];
    __shared__ int sng;

    const int tid = threadIdx.x;   // 0..63
    int c = cat_ids[tid];
    catv[tid] = c;
    keys[tid] = c * 64 + tid;      // unique key, stable within cat
    __syncthreads();

    int mykey = keys[tid];
    int rank = 0;
    for (int j = 0; j < NB; ++j) rank += (keys[j] < mykey) ? 1 : 0;
    order[rank] = tid;
    __syncthreads();

    if (tid == 0) {
        int ng = 0, prev = -1, cnt = 2;
        for (int i = 0; i < NB; ++i) {
            int b  = order[i];
            int cb = catv[b];
            if (cb != prev || cnt == 2) {
                gcat[ng] = cb; gnb[ng] = 0; cnt = 0; prev = cb; ++ng;
            }
            gb[ng - 1][cnt] = b;
            ++cnt; gnb[ng - 1] = cnt;
        }
        sng = ng;
    }
    __syncthreads();

    int ng = sng;
    int base = tid * 8;
    if (tid < ng) {
        int nbv = gnb[tid];
        groups[base + 0] = gcat[tid];
        groups[base + 1] = nbv;
        groups[base + 2] = gb[tid][0];
        groups[base + 3] = (nbv > 1) ? gb[tid][1] : gb[tid][0];  // pad w/ b0
        groups[base + 4] = 0; groups[base + 5] = 0;
        groups[base + 6] = 0; groups[base + 7] = 0;
    } else {
        #pragma unroll
        for (int s = 0; s < 8; ++s) groups[base + s] = 0;        // nb = 0
    }
}

// ---------------------------------------------------------------------------
// K1: a_emb = actions @ W1[cat] + b1 (K=64) and sinusoidal PE, fused.
// Writes x = concat(a_emb, pe) as bf16 [B][T][2H]. grid (B, H/64), block 256.
// ---------------------------------------------------------------------------
__global__ __launch_bounds__(256) void k1_embed(
    const float* __restrict__ actions, const float* __restrict__ W1,
    const float* __restrict__ b1, const int* __restrict__ timesteps,
    const int* __restrict__ cat_ids, bf16_t* __restrict__ x)
{
    __shared__ float act[NT][NA];
    __shared__ float pe[64];

    const int b   = blockIdx.x;
    const int c0  = blockIdx.y * 64;
    const int tid = threadIdx.x;
    const int cat = cat_ids[b];
    const float ts = (float)timesteps[b];

    const float* ab = actions + b * (NT * NA);
    #pragma unroll
    for (int p = 0; p < 16; ++p) {
        int idx = tid + p * 256;
        act[idx >> 6][idx & 63] = ab[idx];
    }
    if (tid < 64) {
        const float kfreq = logf(10000.0f) / 512.0f;
        int c = c0 + tid;
        float v;
        if (c < 512) v = sinf(ts * expf(-(float)c * kfreq));
        else         v = cosf(ts * expf(-(float)(c - 512) * kfreq));
        pe[tid] = v;
    }
    __syncthreads();

    const int cc = tid & 63;
    const int c  = c0 + cc;
    const int t0 = tid >> 6;

    float acc[16];
    const float bias = b1[cat * NH + c];
    #pragma unroll
    for (int i = 0; i < 16; ++i) acc[i] = bias;

    const float* Wp = W1 + (size_t)cat * (NA * NH) + c;
    #pragma unroll 8
    for (int k = 0; k < NA; ++k) {
        float w = Wp[(size_t)k * NH];
        #pragma unroll
        for (int i = 0; i < 16; ++i)
            acc[i] = fmaf(act[t0 + 4 * i][k], w, acc[i]);
    }

    bf16_t* xb = x + (size_t)b * (NT * K2DIM);
    const bf16_t pv = f32_to_bf16(pe[cc]);
    #pragma unroll
    for (int i = 0; i < 16; ++i) {
        int t = t0 + 4 * i;
        xb[(size_t)t * K2DIM + c]      = f32_to_bf16(acc[i]);
        xb[(size_t)t * K2DIM + NH + c] = pv;
    }
}

// ---------------------------------------------------------------------------
// Paired MFMA GEMM. Block: group of <=2 same-cat batches (M = 2x64) x 64 n.
// grid (16 n, 64 groups)  [x = n so active blocks form a contiguous prefix].
// 512 thr = 8 waves = 2 slots x 4 n16-tiles; wave tile 64t x 16n (4x1 frags,
// acc = 16 VGPR). K-chunk 32, DOUBLE-BUFFERED LDS (2 x 12 KB), one barrier
// per chunk; global loads issued one full chunk before their LDS write.
// LDS per buffer: xs 2 slots x [oct][t] 16B units (8 KB, conflict-free both
// sides) + wsm 32k x 64n subtiled [kt 8][nt 4][4][16] (4 KB), B-frags via
// ds_read_b64_tr_b16 (pattern byte-compatible with validated r3/r4 path).
// ---------------------------------------------------------------------------
template<int KDIM, bool SWISH, typename OutT>
__global__ __launch_bounds__(512, 4) void gemm_g2(
    const bf16_t* __restrict__ xin, const float* __restrict__ W,
    const float* __restrict__ bias, const int* __restrict__ groups,
    OutT* __restrict__ out)
{
    __shared__ __align__(128) char lds[2][12288];   // 24 KB total

    const int* grp = groups + blockIdx.y * 8;
    const int nb = grp[1];
    if (nb == 0) return;
    const int cat = grp[0];
    const int ba = grp[2];
    const int bb = grp[3];

    const int n0   = blockIdx.x * 64;
    const int tid  = threadIdx.x;
    const int lane = tid & 63;
    const int wv   = tid >> 6;           // 0..7
    const int l15  = lane & 15;
    const int l4   = lane >> 4;
    const int slot = wv >> 2;            // 0..1  (batch slot)
    const int nf   = wv & 3;             // 0..3  (n16 tile)

    constexpr int NCH = KDIM / 32;

    // --- x staging: thread -> (slot s, t, k-octet), one uint4 ---
    const int xs_s = tid >> 8;           // 0..1
    const int xid  = tid & 255;
    const int xt   = xid >> 2;           // 0..63
    const int xoct = xid & 3;            // 0..3
    const bf16_t* xg = xin + ((size_t)(xs_s ? bb : ba) * NT + xt) * KDIM + xoct * 8;
    const int xl = xs_s * 4096 + xoct * 1024 + xt * 16;

    // --- W staging: thread -> (k row, n-quad), float4 -> uint2 b64 write ---
    const int wk  = tid >> 4;            // 0..31
    const int wq4 = tid & 15;            // 0..15 (n = wq4*4)
    const float* wg = W + (size_t)cat * KDIM * NH + (size_t)wk * NH + n0 + wq4 * 4;
    const int wl = 8192 + ((wk >> 2) * 4 + (wq4 >> 2)) * 128
                        + (wk & 3) * 32 + (wq4 & 3) * 8;

    // --- accumulators ---
    f32x4 acc[4];
    {
        float bv = bias[(size_t)cat * NH + n0 + nf * 16 + l15];
        #pragma unroll
        for (int mf = 0; mf < 4; ++mf) acc[mf] = (f32x4){bv, bv, bv, bv};
    }

    // --- per-wave compute addresses ---
    const unsigned ldsbase = (unsigned)(unsigned long long)&lds[0][0];
    const unsigned trb = ldsbase + 8192u + (unsigned)(l4 * 1024 + nf * 128 + l15 * 8);
    const int aoff = slot * 4096 + l4 * 1024 + l15 * 16;

    uint4  xr;
    float4 wr;
    auto LOAD = [&](int kc) {
        xr = *(const uint4*)(xg + (size_t)kc * 32);
        wr = *(const float4*)(wg + (size_t)kc * 32 * NH);
    };
    auto WRITE = [&](int pw) {
        *(uint4*)(&lds[pw][0] + xl) = xr;
        uint2 pk;
        pk.x = cvt2(wr.x, wr.y);
        pk.y = cvt2(wr.z, wr.w);
        *(uint2*)(&lds[pw][0] + wl) = pk;
    };

    LOAD(0);
    WRITE(0);
    LOAD(1);

    for (int kc = 0; kc < NCH; ++kc) {
        const int p = kc & 1;
        __syncthreads();                    // buf[p] staged; prev reads done

        // A frags (conflict-free b128)
        bf16x8 af0 = *(const bf16x8*)(&lds[p][0] + aoff);
        bf16x8 af1 = *(const bf16x8*)(&lds[p][0] + aoff + 256);
        bf16x8 af2 = *(const bf16x8*)(&lds[p][0] + aoff + 512);
        bf16x8 af3 = *(const bf16x8*)(&lds[p][0] + aoff + 768);
        // B frag via hardware transpose read (verified mapping)
        unsigned a = trb + (unsigned)(p * 12288);
        s16x4 lo, hi;
        asm volatile("ds_read_b64_tr_b16 %0, %1" : "=v"(lo) : "v"(a));
        asm volatile("ds_read_b64_tr_b16 %0, %1 offset:512" : "=v"(hi) : "v"(a));
        bf16x8 bfr = __builtin_shufflevector(lo, hi, 0, 1, 2, 3, 4, 5, 6, 7);

        asm volatile("s_waitcnt lgkmcnt(0)" ::: "memory");
        __builtin_amdgcn_sched_barrier(0);
        acc[0] = __builtin_amdgcn_mfma_f32_16x16x32_bf16(af0, bfr, acc[0], 0, 0, 0);
        acc[1] = __builtin_amdgcn_mfma_f32_16x16x32_bf16(af1, bfr, acc[1], 0, 0, 0);
        acc[2] = __builtin_amdgcn_mfma_f32_16x16x32_bf16(af2, bfr, acc[2], 0, 0, 0);
        acc[3] = __builtin_amdgcn_mfma_f32_16x16x32_bf16(af3, bfr, acc[3], 0, 0, 0);

        if (kc + 1 < NCH) WRITE(p ^ 1);     // regs(kc+1) -> other buffer
        if (kc + 2 < NCH) LOAD(kc + 2);     // latency spans a full chunk
    }

    // epilogue: C/D layout col = lane&15, row = (lane>>4)*4 + reg
    if (slot < nb) {
        const int bout = slot ? bb : ba;
        const int col  = n0 + nf * 16 + l15;
        #pragma unroll
        for (int mf = 0; mf < 4; ++mf) {
            #pragma unroll
            for (int r = 0; r < 4; ++r) {
                int trow = mf * 16 + l4 * 4 + r;
                float h = acc[mf][r];
                if (SWISH) h = h / (1.0f + __expf(-h));
                if constexpr (sizeof(OutT) == 2) {
                    out[((size_t)bout * NT + trow) * NH + col] = (OutT)f32_to_bf16(h);
                } else {
                    out[((size_t)bout * NT + trow) * NH + col] = h;
                }
            }
        }
    }
}

extern "C" void kernel_launch(void* const* d_in, const int* in_sizes, int n_in,
                              void* d_out, int out_size, void* d_ws, size_t ws_size,
                              hipStream_t stream) {
    const float* actions   = (const float*)d_in[0];
    const float* W1        = (const float*)d_in[1];
    const float* b1        = (const float*)d_in[2];
    const float* W2        = (const float*)d_in[3];
    const float* b2        = (const float*)d_in[4];
    const float* W3        = (const float*)d_in[5];
    const float* b3        = (const float*)d_in[6];
    const int*   timesteps = (const int*)d_in[7];
    const int*   cat_ids   = (const int*)d_in[8];
    float* out = (float*)d_out;

    // ws: x bf16 [B][T][2H] (16.8 MB), y bf16 [B][T][H] (8.4 MB), groups (2 KB)
    bf16_t* x = (bf16_t*)d_ws;
    bf16_t* y = x + (size_t)NB * NT * K2DIM;
    int* groups = (int*)(y + (size_t)NB * NT * NH);

    make_groups<<<1, 64, 0, stream>>>(cat_ids, groups);
    k1_embed<<<dim3(NB, NH / 64), 256, 0, stream>>>(actions, W1, b1, timesteps, cat_ids, x);
    gemm_g2<K2DIM, true,  bf16_t><<<dim3(16, 64), 512, 0, stream>>>(x, W2, b2, groups, y);
    gemm_g2<NH,    false, float ><<<dim3(16, 64), 512, 0, stream>>>(y, W3, b3, groups, out);
}